// Round 11
// baseline (127.304 us; speedup 1.0000x reference)
//
#include <hip/hip_runtime.h>
#include <hip/hip_fp16.h>
#include <math.h>

#define NQ 12
#define DIM 4096
#define NL 4
#define THREADS 256
#define SWZC(e) ((e) ^ (((e) >> 3) & 14) ^ (((e) >> 7) & 15))
#define WAVEFENCE() { __builtin_amdgcn_wave_barrier(); __builtin_amdgcn_sched_barrier(0); }

typedef float v2f __attribute__((ext_vector_type(2)));

__device__ __forceinline__ v2f pkfma(v2f a, v2f b, v2f c) {
    v2f d; asm("v_pk_fma_f32 %0, %1, %2, %3" : "=v"(d) : "v"(a), "v"(b), "v"(c)); return d;
}
__device__ __forceinline__ v2f pkmul(v2f a, v2f b) {
    v2f d; asm("v_pk_mul_f32 %0, %1, %2" : "=v"(d) : "v"(a), "v"(b)); return d;
}
__device__ __forceinline__ v2f pkadd(v2f a, v2f b) {
    v2f d; asm("v_pk_add_f32 %0, %1, %2" : "=v"(d) : "v"(a), "v"(b)); return d;
}
__device__ __forceinline__ float2 cmulS(float2 a, float2 b) {
    return make_float2(fmaf(a.x, b.x, -a.y * b.y), fmaf(a.x, b.y, a.y * b.x));
}

// f16 transit packing: (reA,reB) and (imA,imB) as two half2 in one uint2 (8B)
__device__ __forceinline__ uint2 packh(v2f re, v2f im) {
    __half2 a = __floats2half2_rn(re[0], re[1]);
    __half2 b = __floats2half2_rn(im[0], im[1]);
    uint2 r;
    r.x = __builtin_bit_cast(unsigned int, a);
    r.y = __builtin_bit_cast(unsigned int, b);
    return r;
}
__device__ __forceinline__ void unpackh(uint2 t, v2f* re, v2f* im) {
    float2 fa = __half22float2(__builtin_bit_cast(__half2, t.x));
    float2 fb = __half22float2(__builtin_bit_cast(__half2, t.y));
    v2f r = {fa.x, fa.y}, i = {fb.x, fb.y};
    *re = r; *im = i;
}

struct C4 { v2f r, i, ni, nr; };   // broadcast (re,re),(im,im),(-im,-im),(-re,-re)

#define CMUL4(orE, orI, KR, KNI, KI, xre, xim) \
    { orE = pkfma(KNI, xim, pkmul(KR, xre)); orI = pkfma(KI, xre, pkmul(KR, xim)); }
#define CMAC4(orE, orI, KR, KNI, KI, xre, xim) \
    { orE = pkfma(KR, xre, pkfma(KNI, xim, orE)); orI = pkfma(KR, xim, pkfma(KI, xre, orI)); }

// SU(2) 2-stage 4x4 pair-gate; even-CNOT baked in (outputs C<-y3, D<-y2).
#define QUADBODY(A_, B_, C_, D_) { \
    v2f z0r,z0i,z1r,z1i,z2r,z2i,z3r,z3i; \
    CMUL4(z0r,z0i, la.r, la.ni, la.i, sre[A_], sim[A_]); CMAC4(z0r,z0i, lb.r, lb.ni, lb.i, sre[B_], sim[B_]); \
    CMUL4(z1r,z1i, lb.nr, lb.ni, lb.i, sre[A_], sim[A_]); CMAC4(z1r,z1i, la.r, la.i, la.ni, sre[B_], sim[B_]); \
    CMUL4(z2r,z2i, la.r, la.ni, la.i, sre[C_], sim[C_]); CMAC4(z2r,z2i, lb.r, lb.ni, lb.i, sre[D_], sim[D_]); \
    CMUL4(z3r,z3i, lb.nr, lb.ni, lb.i, sre[C_], sim[C_]); CMAC4(z3r,z3i, la.r, la.i, la.ni, sre[D_], sim[D_]); \
    v2f y0r,y0i,y1r,y1i,y2r,y2i,y3r,y3i; \
    CMUL4(y0r,y0i, ha.r, ha.ni, ha.i, z0r, z0i); CMAC4(y0r,y0i, hb.r, hb.ni, hb.i, z2r, z2i); \
    CMUL4(y1r,y1i, ha.r, ha.ni, ha.i, z1r, z1i); CMAC4(y1r,y1i, hb.r, hb.ni, hb.i, z3r, z3i); \
    CMUL4(y2r,y2i, hb.nr, hb.ni, hb.i, z0r, z0i); CMAC4(y2r,y2i, ha.r, ha.i, ha.ni, z2r, z2i); \
    CMUL4(y3r,y3i, hb.nr, hb.ni, hb.i, z1r, z1i); CMAC4(y3r,y3i, ha.r, ha.i, ha.ni, z3r, z3i); \
    sre[A_]=y0r; sim[A_]=y0i; sre[B_]=y1r; sim[B_]=y1i; \
    sre[C_]=y3r; sim[C_]=y3i; sre[D_]=y2r; sim[D_]=y2i; }

__device__ __forceinline__ void pass_hi(v2f* sre, v2f* sim, const v2f (*U)[4]) {
    C4 la={U[0][0],U[0][1],U[0][2],U[0][3]}, lb={U[1][0],U[1][1],U[1][2],U[1][3]},
       ha={U[2][0],U[2][1],U[2][2],U[2][3]}, hb={U[3][0],U[3][1],U[3][2],U[3][3]};
    QUADBODY(0,4,8,12) QUADBODY(1,5,9,13) QUADBODY(2,6,10,14) QUADBODY(3,7,11,15)
}
__device__ __forceinline__ void pass_lo(v2f* sre, v2f* sim, const v2f (*U)[4]) {
    C4 la={U[0][0],U[0][1],U[0][2],U[0][3]}, lb={U[1][0],U[1][1],U[1][2],U[1][3]},
       ha={U[2][0],U[2][1],U[2][2],U[2][3]}, hb={U[3][0],U[3][1],U[3][2],U[3][3]};
    QUADBODY(0,1,2,3) QUADBODY(4,5,6,7) QUADBODY(8,9,10,11) QUADBODY(12,13,14,15)
}

__global__ __attribute__((amdgpu_flat_work_group_size(256, 256), amdgpu_num_vgpr(80)))
void vqc_kernel(const float* __restrict__ features,
                const float* __restrict__ theta,
                const float* __restrict__ alpha,
                float* __restrict__ out)
{
    __shared__ uint2 scrH[DIM];           // 32 KB f16-packed transit (reA,reB,imA,imB)
    __shared__ v2f Upk[24][4][4];         // 3 KB coeff quads (f32 broadcast)
    __shared__ v2f red[12 * 4];
    __shared__ float wez[12];

    // build-phase tables aliased into scrH (dead before first transition store)
    float2* cs = (float2*)scrH;                                     // [0,1152)
    float2 (*U48)[4] = (float2(*)[4])((char*)scrH + 1152);          // [1152,2688)
    float2 (*enc)[2] = (float2(*)[2])((char*)scrH + 2688);          // [2688,3072)
    float2 (*pairT)[4] = (float2(*)[4])((char*)scrH + 3072);        // [3072,3456)
    float2* loc = (float2*)((char*)scrH + 3456);                    // [3456,3712)

    const int tid = threadIdx.x;
    const bool special = (blockIdx.x == 0);   // shared h_angle_rx circuit (|+>^12 up to phase)
    const int gA = special ? 0 : 2 * ((int)blockIdx.x - 1);
    const int gB = gA + 1;

    // ---- stage 1: theta sincos + encoding states (2 circuits) ----
    if (tid < NL * NQ * 3) {
        float s, c; sincosf(0.5f * theta[tid], &s, &c);
        cs[tid] = make_float2(c, s);
    }
    if (tid >= 160 && tid < 184) {
        int c_ = (tid - 160) / 12, q = (tid - 160) % 12;
        const float r_ = 0.70710678118654752f;
        float2 a0, a1;
        if (special) { a0 = make_float2(r_, 0.f); a1 = a0; }
        else {
            int g = c_ ? gB : gA;
            int esl = g % 3, b = g / 3;
            float f = features[b * NQ + q];
            float s, c; sincosf(0.5f * f, &s, &c);
            if (esl == 0)      { a0 = make_float2(c, 0.f); a1 = make_float2(0.f, -s); }
            else if (esl == 1) { a0 = make_float2(c, 0.f); a1 = make_float2(s, 0.f); }
            else               { a0 = make_float2((c-s)*r_, 0.f); a1 = make_float2((c+s)*r_, 0.f); }
        }
        enc[c_ * NQ + q][0] = a0; enc[c_ * NQ + q][1] = a1;
    }
    __syncthreads();

    // ---- stage 2: fused U = RZ*RY*RX + pair tables ----
    if (tid < NL * NQ) {
        float c0 = cs[tid*3+0].x, s0 = cs[tid*3+0].y;
        float c1 = cs[tid*3+1].x, s1 = cs[tid*3+1].y;
        float c2 = cs[tid*3+2].x, s2 = cs[tid*3+2].y;
        float2 a00 = make_float2( c1*c0,  s1*s0);
        float2 a01 = make_float2(-s1*c0, -c1*s0);
        float2 a10 = make_float2( s1*c0, -c1*s0);
        float2 a11 = make_float2( c1*c0, -s1*s0);
        float2 ep = make_float2(c2, -s2), em = make_float2(c2, s2);
        U48[tid][0] = cmulS(ep, a00); U48[tid][1] = cmulS(ep, a01);
        U48[tid][2] = cmulS(em, a10); U48[tid][3] = cmulS(em, a11);
    }
    if (tid >= 64 && tid < 112) {
        int x = tid - 64;
        int c_ = x / 24, y = x % 24, p = y >> 2, v = y & 3;
        pairT[c_ * 6 + p][v] = cmulS(enc[c_*NQ + 2*p][v >> 1], enc[c_*NQ + 2*p + 1][v & 1]);
    }
    __syncthreads();

    // ---- stage 3: packed SU(2) coeff quads + local product table ----
    for (int idx = tid; idx < 384; idx += THREADS) {
        int p = idx >> 4, rest = idx & 15, c = rest >> 2, comp = rest & 3;
        int l = p / 6, m = p % 6;
        int q = (c < 2) ? (2*m + 1) : (2*m);
        float2 u = U48[l*NQ + q][c & 1];
        float xv = (comp == 0) ? u.x : (comp == 1) ? u.y : (comp == 2) ? -u.y : -u.x;
        v2f vv = {xv, xv};
        Upk[p][c][comp] = vv;
    }
    if (tid >= 192 && tid < 224) {
        int x = tid - 192; int c_ = x >> 4, j = x & 15;
        loc[c_ * 16 + j] = cmulS(pairT[c_*6 + 4][j >> 2], pairT[c_*6 + 5][j & 3]);
    }
    __syncthreads();

    // ---- build product state into LA registers (i = tid<<4 | j) ----
    v2f sre[16], sim[16];
    {
        int t = tid;
        float2 preA = cmulS(cmulS(pairT[0][(t>>6)&3], pairT[1][(t>>4)&3]),
                            cmulS(pairT[2][(t>>2)&3], pairT[3][t&3]));
        float2 preB = cmulS(cmulS(pairT[6][(t>>6)&3], pairT[7][(t>>4)&3]),
                            cmulS(pairT[8][(t>>2)&3], pairT[9][t&3]));
        #pragma unroll
        for (int j = 0; j < 16; ++j) {
            float2 aA = cmulS(preA, loc[j]);
            float2 aB = cmulS(preB, loc[16 + j]);
            v2f r = {aA.x, aB.x}, ii = {aA.y, aB.y};
            sre[j] = r; sim[j] = ii;
        }
    }
    __syncthreads();   // tables (aliased in scrH) dead before first transition store

    const int ba = SWZC(tid << 4);
    const int bb = SWZC((((tid >> 4) << 8) | (tid & 15)));
    const int bc = SWZC(tid);
    const int sx = (tid << 4) ^ ((tid & 1) << 3) ^ (((tid >> 2) & 1) << 5)
                             ^ (((tid >> 4) & 1) << 7) ^ (((tid >> 6) & 1) << 9);
    const int bs = SWZC(sx);

    // ---- 4 variational layers: f16 transit, minimal barrier schedule ----
    // gathers are quad-major (j = 4*rr + qq) so pass_hi's first QUADBODY operands
    // (j = 0,4,8,12) are the first four ds_reads issued -> partial lgkmcnt overlap
    #pragma unroll 1
    for (int l = 0; l < NL; ++l) {
        if (l > 0) {
            // LA entry: sigma-folded gather (cross-thread reads of T_CA stores)
            #pragma unroll
            for (int qq = 0; qq < 4; ++qq)
            #pragma unroll
            for (int rr = 0; rr < 4; ++rr) {
                int j = 4 * rr + qq;
                int a = bs ^ (j ^ ((j >> 1) & 2));
                unpackh(scrH[a], &sre[j], &sim[j]);
            }
            __syncthreads();   // all gathers done before T_AB overwrites (cross WAR)
        }
        // LA: P4 (bits 3,2), P5 (bits 1,0)
        pass_hi(sre, sim, Upk[l*6 + 4]);
        pass_lo(sre, sim, Upk[l*6 + 5]);
        // T_AB: write own 16-block (ba), read wave-local cross (bb)
        WAVEFENCE();
        #pragma unroll
        for (int j = 0; j < 16; ++j) scrH[ba ^ j] = packh(sre[j], sim[j]);
        WAVEFENCE();
        #pragma unroll
        for (int qq = 0; qq < 4; ++qq)
        #pragma unroll
        for (int rr = 0; rr < 4; ++rr) {
            int j = 4 * rr + qq;
            unpackh(scrH[bb ^ SWZC(j << 4)], &sre[j], &sim[j]);
        }
        // LB: P2 (bits 7,6), P3 (bits 5,4)
        pass_hi(sre, sim, Upk[l*6 + 2]);
        pass_lo(sre, sim, Upk[l*6 + 3]);
        // T_BC: write own set (bb), cross gather (bc)
        WAVEFENCE();
        #pragma unroll
        for (int j = 0; j < 16; ++j) scrH[bb ^ SWZC(j << 4)] = packh(sre[j], sim[j]);
        __syncthreads();
        #pragma unroll
        for (int qq = 0; qq < 4; ++qq)
        #pragma unroll
        for (int rr = 0; rr < 4; ++rr) {
            int j = 4 * rr + qq;
            unpackh(scrH[bc ^ SWZC(j << 8)], &sre[j], &sim[j]);
        }
        // LC: P0 (bits 11,10), P1 (bits 9,8)
        pass_hi(sre, sim, Upk[l*6 + 0]);
        pass_lo(sre, sim, Upk[l*6 + 1]);
        if (l < NL - 1) {
            // T_CA: write own set (bc); next LA gather is cross -> barrier after
            WAVEFENCE();
            #pragma unroll
            for (int j = 0; j < 16; ++j) scrH[bc ^ SWZC(j << 8)] = packh(sre[j], sim[j]);
            __syncthreads();
        }
    }

    // ---- measurement in LC, layer-3 sigma folded into sign indices ----
    v2f s0 = {0.f,0.f}, s1 = {0.f,0.f}, s2 = {0.f,0.f}, s3 = {0.f,0.f}, psum = {0.f,0.f};
    {
        const v2f MONE = {-1.f, -1.f};
        #pragma unroll
        for (int j = 0; j < 16; ++j) {
            v2f p = pkfma(sim[j], sim[j], pkmul(sre[j], sre[j]));
            psum = pkadd(psum, p);
            if (j & 8)                        s0 = pkfma(p, MONE, s0); else s0 = pkadd(s0, p);
            if (j & 4)                        s1 = pkfma(p, MONE, s1); else s1 = pkadd(s1, p);
            if ((((j >> 1) ^ (j >> 2)) & 1))  s2 = pkfma(p, MONE, s2); else s2 = pkadd(s2, p);
            if (j & 1)                        s3 = pkfma(p, MONE, s3); else s3 = pkadd(s3, p);
        }
    }
    v2f vals[12];
    {
        int t = tid;
        int mt = t ^ ((t >> 1) & 0xAA);
        vals[0] = s0; vals[1] = s1; vals[2] = s2; vals[3] = s3;
        vals[4]  = ((t >> 7) & 1)  ? -s3 : s3;
        vals[5]  = ((mt >> 6) & 1) ? -psum : psum;
        vals[6]  = ((mt >> 5) & 1) ? -psum : psum;
        vals[7]  = ((mt >> 4) & 1) ? -psum : psum;
        vals[8]  = ((mt >> 3) & 1) ? -psum : psum;
        vals[9]  = ((mt >> 2) & 1) ? -psum : psum;
        vals[10] = ((mt >> 1) & 1) ? -psum : psum;
        vals[11] = (mt & 1)        ? -psum : psum;
    }
    const int lane = tid & 63, wv = tid >> 6;
    #pragma unroll
    for (int q = 0; q < 12; ++q) {
        v2f v = vals[q];
        #pragma unroll
        for (int mm = 32; mm >= 1; mm >>= 1) {
            v.x += __shfl_xor(v.x, mm, 64);
            v.y += __shfl_xor(v.y, mm, 64);
        }
        if (lane == 0) red[q * 4 + wv] = v;
    }
    __syncthreads();

    if (tid < 12) {
        v2f v = pkadd(pkadd(red[tid*4+0], red[tid*4+1]), pkadd(red[tid*4+2], red[tid*4+3]));
        float A0 = alpha[0], A1 = alpha[1], A2 = alpha[2], A3 = alpha[3];
        float mx = fmaxf(fmaxf(A0, A1), fmaxf(A2, A3));
        float E0 = expf(A0-mx), E1 = expf(A1-mx), E2 = expf(A2-mx), E3 = expf(A3-mx);
        float den = E0 + E1 + E2 + E3;
        if (special) {
            wez[tid] = (E2 / den) * v.x;
        } else {
            int eslA = gA % 3, bA = gA / 3;
            int eslB = gB % 3, bB = gB / 3;
            float wA = ((eslA == 0) ? E0 : (eslA == 1) ? E1 : E3) / den;
            float wB = ((eslB == 0) ? E0 : (eslB == 1) ? E1 : E3) / den;
            atomicAdd(out + bA * NQ + tid, wA * v.x);
            atomicAdd(out + bB * NQ + tid, wB * v.y);
        }
    }
    if (special) {
        __syncthreads();
        for (int bb2 = tid; bb2 < 1024; bb2 += THREADS) {
            #pragma unroll
            for (int q = 0; q < NQ; ++q)
                atomicAdd(out + bb2 * NQ + q, wez[q]);
        }
    }
}

extern "C" void kernel_launch(void* const* d_in, const int* in_sizes, int n_in,
                              void* d_out, int out_size, void* d_ws, size_t ws_size,
                              hipStream_t stream) {
    const float* features = (const float*)d_in[0];
    const float* theta    = (const float*)d_in[1];
    const float* alpha    = (const float*)d_in[2];
    float* out = (float*)d_out;

    hipMemsetAsync(out, 0, (size_t)out_size * sizeof(float), stream);
    vqc_kernel<<<dim3(1537), THREADS, 0, stream>>>(features, theta, alpha, out);
}

// Round 13
// 123.612 us; speedup vs baseline: 1.0299x; 1.0299x over previous
//
#include <hip/hip_runtime.h>
#include <hip/hip_fp16.h>
#include <math.h>

#define NQ 12
#define DIM 4096
#define NL 4
#define THREADS 256
#define SWZC(e) ((e) ^ (((e) >> 3) & 14) ^ (((e) >> 7) & 15))
#define WAVEFENCE() { __builtin_amdgcn_wave_barrier(); __builtin_amdgcn_sched_barrier(0); }

typedef float v2f __attribute__((ext_vector_type(2)));

__device__ __forceinline__ v2f pkfma(v2f a, v2f b, v2f c) {
    v2f d; asm("v_pk_fma_f32 %0, %1, %2, %3" : "=v"(d) : "v"(a), "v"(b), "v"(c)); return d;
}
__device__ __forceinline__ v2f pkfman(v2f a, v2f b, v2f c) {   // (-a)*b + c
    v2f d; asm("v_pk_fma_f32 %0, %1, %2, %3 neg_lo:[1,0,0] neg_hi:[1,0,0]" : "=v"(d) : "v"(a), "v"(b), "v"(c)); return d;
}
__device__ __forceinline__ v2f pkmul(v2f a, v2f b) {
    v2f d; asm("v_pk_mul_f32 %0, %1, %2" : "=v"(d) : "v"(a), "v"(b)); return d;
}
__device__ __forceinline__ v2f pkmuln(v2f a, v2f b) {          // (-a)*b
    v2f d; asm("v_pk_mul_f32 %0, %1, %2 neg_lo:[1,0,0] neg_hi:[1,0,0]" : "=v"(d) : "v"(a), "v"(b)); return d;
}
__device__ __forceinline__ v2f pkadd(v2f a, v2f b) {
    v2f d; asm("v_pk_add_f32 %0, %1, %2" : "=v"(d) : "v"(a), "v"(b)); return d;
}
__device__ __forceinline__ float2 cmulS(float2 a, float2 b) {
    return make_float2(fmaf(a.x, b.x, -a.y * b.y), fmaf(a.x, b.y, a.y * b.x));
}

// f16 transit packing: (reA,reB) and (imA,imB) as two half2 in one uint2 (8B)
__device__ __forceinline__ uint2 packh(v2f re, v2f im) {
    __half2 a = __floats2half2_rn(re[0], re[1]);
    __half2 b = __floats2half2_rn(im[0], im[1]);
    uint2 r;
    r.x = __builtin_bit_cast(unsigned int, a);
    r.y = __builtin_bit_cast(unsigned int, b);
    return r;
}
__device__ __forceinline__ void unpackh(uint2 t, v2f* re, v2f* im) {
    float2 fa = __half22float2(__builtin_bit_cast(__half2, t.x));
    float2 fb = __half22float2(__builtin_bit_cast(__half2, t.y));
    v2f r = {fa.x, fa.y}, i = {fb.x, fb.y};
    *re = r; *im = i;
}

struct C2 { v2f r, i; };   // broadcast (re,re),(im,im); negation via asm modifiers

// y  = K*x        : E = r*xre - i*xim ; I = i*xre + r*xim
#define CMUL_STD(orE, orI, K, xre, xim) \
    { orE = pkfman(K.i, xim, pkmul(K.r, xre)); orI = pkfma(K.i, xre, pkmul(K.r, xim)); }
// y += K*x
#define CMAC_STD(orE, orI, K, xre, xim) \
    { orE = pkfma(K.r, xre, pkfman(K.i, xim, orE)); orI = pkfma(K.r, xim, pkfma(K.i, xre, orI)); }
// y  = -conj(K)*x : E = -r*xre - i*xim ; I = i*xre - r*xim
#define CMUL_NCJ(orE, orI, K, xre, xim) \
    { orE = pkfman(K.i, xim, pkmuln(K.r, xre)); orI = pkfma(K.i, xre, pkmuln(K.r, xim)); }
// y += conj(K)*x  : E += r*xre + i*xim ; I += r*xim - i*xre
#define CMAC_CJ(orE, orI, K, xre, xim) \
    { orE = pkfma(K.r, xre, pkfma(K.i, xim, orE)); orI = pkfma(K.r, xim, pkfman(K.i, xre, orI)); }

// SU(2) 2-stage 4x4 pair-gate; even-CNOT baked in (outputs C<-y3, D<-y2).
#define QUADBODY(A_, B_, C_, D_) { \
    v2f z0r,z0i,z1r,z1i,z2r,z2i,z3r,z3i; \
    CMUL_STD(z0r,z0i, la, sre[A_], sim[A_]); CMAC_STD(z0r,z0i, lb, sre[B_], sim[B_]); \
    CMUL_NCJ(z1r,z1i, lb, sre[A_], sim[A_]); CMAC_CJ (z1r,z1i, la, sre[B_], sim[B_]); \
    CMUL_STD(z2r,z2i, la, sre[C_], sim[C_]); CMAC_STD(z2r,z2i, lb, sre[D_], sim[D_]); \
    CMUL_NCJ(z3r,z3i, lb, sre[C_], sim[C_]); CMAC_CJ (z3r,z3i, la, sre[D_], sim[D_]); \
    v2f y0r,y0i,y1r,y1i,y2r,y2i,y3r,y3i; \
    CMUL_STD(y0r,y0i, ha, z0r,z0i); CMAC_STD(y0r,y0i, hb, z2r,z2i); \
    CMUL_STD(y1r,y1i, ha, z1r,z1i); CMAC_STD(y1r,y1i, hb, z3r,z3i); \
    CMUL_NCJ(y2r,y2i, hb, z0r,z0i); CMAC_CJ (y2r,y2i, ha, z2r,z2i); \
    CMUL_NCJ(y3r,y3i, hb, z1r,z1i); CMAC_CJ (y3r,y3i, ha, z3r,z3i); \
    sre[A_]=y0r; sim[A_]=y0i; sre[B_]=y1r; sim[B_]=y1i; \
    sre[C_]=y3r; sim[C_]=y3i; sre[D_]=y2r; sim[D_]=y2i; }

#define LOADU \
    C2 la={U[0][0],U[0][1]}, lb={U[1][0],U[1][1]}, \
       ha={U[2][0],U[2][1]}, hb={U[3][0],U[3][1]};

__device__ __forceinline__ void pass_hi(v2f* sre, v2f* sim, const v2f (*U)[2]) {
    LOADU
    QUADBODY(0,4,8,12) QUADBODY(1,5,9,13) QUADBODY(2,6,10,14) QUADBODY(3,7,11,15)
}
__device__ __forceinline__ void pass_lo(v2f* sre, v2f* sim, const v2f (*U)[2]) {
    LOADU
    QUADBODY(0,1,2,3) QUADBODY(4,5,6,7) QUADBODY(8,9,10,11) QUADBODY(12,13,14,15)
}

__global__ __launch_bounds__(THREADS, 2)
void vqc_kernel(const float* __restrict__ features,
                const float* __restrict__ theta,
                const float* __restrict__ alpha,
                float* __restrict__ out)
{
    __shared__ uint2 scrH[DIM];           // 32 KB f16-packed transit (reA,reB,imA,imB)
    __shared__ v2f Upk[24][4][2];         // 1.5 KB coeff (r,i) pairs
    __shared__ v2f red[12 * 4];
    __shared__ float wez[12];

    // build-phase tables aliased into scrH (dead before first transition store)
    float2* cs = (float2*)scrH;                                     // [0,1152)
    float2 (*U48)[4] = (float2(*)[4])((char*)scrH + 1152);          // [1152,2688)
    float2 (*enc)[2] = (float2(*)[2])((char*)scrH + 2688);          // [2688,3072)
    float2 (*pairT)[4] = (float2(*)[4])((char*)scrH + 3072);        // [3072,3456)
    float2* loc = (float2*)((char*)scrH + 3456);                    // [3456,3712)

    const int tid = threadIdx.x;
    const bool special = (blockIdx.x == 0);   // shared h_angle_rx circuit (|+>^12 up to phase)
    const int gA = special ? 0 : 2 * ((int)blockIdx.x - 1);
    const int gB = gA + 1;

    // ---- stage 1: theta sincos + encoding states (2 circuits) ----
    if (tid < NL * NQ * 3) {
        float s, c; sincosf(0.5f * theta[tid], &s, &c);
        cs[tid] = make_float2(c, s);
    }
    if (tid >= 160 && tid < 184) {
        int c_ = (tid - 160) / 12, q = (tid - 160) % 12;
        const float r_ = 0.70710678118654752f;
        float2 a0, a1;
        if (special) { a0 = make_float2(r_, 0.f); a1 = a0; }
        else {
            int g = c_ ? gB : gA;
            int esl = g % 3, b = g / 3;
            float f = features[b * NQ + q];
            float s, c; sincosf(0.5f * f, &s, &c);
            if (esl == 0)      { a0 = make_float2(c, 0.f); a1 = make_float2(0.f, -s); }
            else if (esl == 1) { a0 = make_float2(c, 0.f); a1 = make_float2(s, 0.f); }
            else               { a0 = make_float2((c-s)*r_, 0.f); a1 = make_float2((c+s)*r_, 0.f); }
        }
        enc[c_ * NQ + q][0] = a0; enc[c_ * NQ + q][1] = a1;
    }
    __syncthreads();

    // ---- stage 2: fused U = RZ*RY*RX + pair tables ----
    if (tid < NL * NQ) {
        float c0 = cs[tid*3+0].x, s0 = cs[tid*3+0].y;
        float c1 = cs[tid*3+1].x, s1 = cs[tid*3+1].y;
        float c2 = cs[tid*3+2].x, s2 = cs[tid*3+2].y;
        float2 a00 = make_float2( c1*c0,  s1*s0);
        float2 a01 = make_float2(-s1*c0, -c1*s0);
        float2 a10 = make_float2( s1*c0, -c1*s0);
        float2 a11 = make_float2( c1*c0, -s1*s0);
        float2 ep = make_float2(c2, -s2), em = make_float2(c2, s2);
        U48[tid][0] = cmulS(ep, a00); U48[tid][1] = cmulS(ep, a01);
        U48[tid][2] = cmulS(em, a10); U48[tid][3] = cmulS(em, a11);
    }
    if (tid >= 64 && tid < 112) {
        int x = tid - 64;
        int c_ = x / 24, y = x % 24, p = y >> 2, v = y & 3;
        pairT[c_ * 6 + p][v] = cmulS(enc[c_*NQ + 2*p][v >> 1], enc[c_*NQ + 2*p + 1][v & 1]);
    }
    __syncthreads();

    // ---- stage 3: packed SU(2) coeff (r,i) pairs + local product table ----
    if (tid < 192) {
        int p = tid >> 3, rest = tid & 7, c = rest >> 1, comp = rest & 1;
        int l = p / 6, m = p % 6;
        int q = (c < 2) ? (2*m + 1) : (2*m);       // c0,c1: lo qubit a,b; c2,c3: hi qubit a,b
        float2 u = U48[l*NQ + q][c & 1];
        float xv = comp ? u.y : u.x;
        v2f vv = {xv, xv};
        Upk[p][c][comp] = vv;
    }
    if (tid >= 192 && tid < 224) {
        int x = tid - 192; int c_ = x >> 4, j = x & 15;
        loc[c_ * 16 + j] = cmulS(pairT[c_*6 + 4][j >> 2], pairT[c_*6 + 5][j & 3]);
    }
    __syncthreads();

    // ---- build product state into LA registers (i = tid<<4 | j) ----
    v2f sre[16], sim[16];
    {
        int t = tid;
        float2 preA = cmulS(cmulS(pairT[0][(t>>6)&3], pairT[1][(t>>4)&3]),
                            cmulS(pairT[2][(t>>2)&3], pairT[3][t&3]));
        float2 preB = cmulS(cmulS(pairT[6][(t>>6)&3], pairT[7][(t>>4)&3]),
                            cmulS(pairT[8][(t>>2)&3], pairT[9][t&3]));
        #pragma unroll
        for (int j = 0; j < 16; ++j) {
            float2 aA = cmulS(preA, loc[j]);
            float2 aB = cmulS(preB, loc[16 + j]);
            v2f r = {aA.x, aB.x}, ii = {aA.y, aB.y};
            sre[j] = r; sim[j] = ii;
        }
    }
    __syncthreads();   // tables (aliased in scrH) dead before first transition store

    const int ba = SWZC(tid << 4);
    const int bb = SWZC((((tid >> 4) << 8) | (tid & 15)));
    const int bc = SWZC(tid);
    const int sx = (tid << 4) ^ ((tid & 1) << 3) ^ (((tid >> 2) & 1) << 5)
                             ^ (((tid >> 4) & 1) << 7) ^ (((tid >> 6) & 1) << 9);
    const int bs = SWZC(sx);

    // ---- 4 variational layers: f16 transit, minimal barrier schedule ----
    #pragma unroll 1
    for (int l = 0; l < NL; ++l) {
        if (l > 0) {
            // LA entry: sigma-folded gather (cross-thread reads of T_CA stores)
            #pragma unroll
            for (int qq = 0; qq < 4; ++qq)
            #pragma unroll
            for (int rr = 0; rr < 4; ++rr) {
                int j = 4 * rr + qq;
                int a = bs ^ (j ^ ((j >> 1) & 2));
                unpackh(scrH[a], &sre[j], &sim[j]);
            }
            __syncthreads();   // all gathers done before T_AB overwrites (cross WAR)
        }
        // LA: P4 (bits 3,2), P5 (bits 1,0)
        pass_hi(sre, sim, Upk[l*6 + 4]);
        pass_lo(sre, sim, Upk[l*6 + 5]);
        // T_AB: write own 16-block (ba), read wave-local cross (bb)
        WAVEFENCE();
        #pragma unroll
        for (int j = 0; j < 16; ++j) scrH[ba ^ j] = packh(sre[j], sim[j]);
        WAVEFENCE();
        #pragma unroll
        for (int qq = 0; qq < 4; ++qq)
        #pragma unroll
        for (int rr = 0; rr < 4; ++rr) {
            int j = 4 * rr + qq;
            unpackh(scrH[bb ^ SWZC(j << 4)], &sre[j], &sim[j]);
        }
        // LB: P2 (bits 7,6), P3 (bits 5,4)
        pass_hi(sre, sim, Upk[l*6 + 2]);
        pass_lo(sre, sim, Upk[l*6 + 3]);
        // T_BC: write own set (bb), cross gather (bc)
        WAVEFENCE();
        #pragma unroll
        for (int j = 0; j < 16; ++j) scrH[bb ^ SWZC(j << 4)] = packh(sre[j], sim[j]);
        __syncthreads();
        #pragma unroll
        for (int qq = 0; qq < 4; ++qq)
        #pragma unroll
        for (int rr = 0; rr < 4; ++rr) {
            int j = 4 * rr + qq;
            unpackh(scrH[bc ^ SWZC(j << 8)], &sre[j], &sim[j]);
        }
        // LC: P0 (bits 11,10), P1 (bits 9,8)
        pass_hi(sre, sim, Upk[l*6 + 0]);
        pass_lo(sre, sim, Upk[l*6 + 1]);
        if (l < NL - 1) {
            // T_CA: write own set (bc); next LA gather is cross -> barrier after
            WAVEFENCE();
            #pragma unroll
            for (int j = 0; j < 16; ++j) scrH[bc ^ SWZC(j << 8)] = packh(sre[j], sim[j]);
            __syncthreads();
        }
    }

    // ---- measurement in LC, layer-3 sigma folded into sign indices ----
    v2f s0 = {0.f,0.f}, s1 = {0.f,0.f}, s2 = {0.f,0.f}, s3 = {0.f,0.f}, psum = {0.f,0.f};
    {
        const v2f MONE = {-1.f, -1.f};
        #pragma unroll
        for (int j = 0; j < 16; ++j) {
            v2f p = pkfma(sim[j], sim[j], pkmul(sre[j], sre[j]));
            psum = pkadd(psum, p);
            if (j & 8)                        s0 = pkfma(p, MONE, s0); else s0 = pkadd(s0, p);
            if (j & 4)                        s1 = pkfma(p, MONE, s1); else s1 = pkadd(s1, p);
            if ((((j >> 1) ^ (j >> 2)) & 1))  s2 = pkfma(p, MONE, s2); else s2 = pkadd(s2, p);
            if (j & 1)                        s3 = pkfma(p, MONE, s3); else s3 = pkadd(s3, p);
        }
    }
    v2f vals[12];
    {
        int t = tid;
        int mt = t ^ ((t >> 1) & 0xAA);
        vals[0] = s0; vals[1] = s1; vals[2] = s2; vals[3] = s3;
        vals[4]  = ((t >> 7) & 1)  ? -s3 : s3;
        vals[5]  = ((mt >> 6) & 1) ? -psum : psum;
        vals[6]  = ((mt >> 5) & 1) ? -psum : psum;
        vals[7]  = ((mt >> 4) & 1) ? -psum : psum;
        vals[8]  = ((mt >> 3) & 1) ? -psum : psum;
        vals[9]  = ((mt >> 2) & 1) ? -psum : psum;
        vals[10] = ((mt >> 1) & 1) ? -psum : psum;
        vals[11] = (mt & 1)        ? -psum : psum;
    }
    const int lane = tid & 63, wv = tid >> 6;
    #pragma unroll
    for (int q = 0; q < 12; ++q) {
        v2f v = vals[q];
        #pragma unroll
        for (int mm = 32; mm >= 1; mm >>= 1) {
            v.x += __shfl_xor(v.x, mm, 64);
            v.y += __shfl_xor(v.y, mm, 64);
        }
        if (lane == 0) red[q * 4 + wv] = v;
    }
    __syncthreads();

    if (tid < 12) {
        v2f v = pkadd(pkadd(red[tid*4+0], red[tid*4+1]), pkadd(red[tid*4+2], red[tid*4+3]));
        float A0 = alpha[0], A1 = alpha[1], A2 = alpha[2], A3 = alpha[3];
        float mx = fmaxf(fmaxf(A0, A1), fmaxf(A2, A3));
        float E0 = expf(A0-mx), E1 = expf(A1-mx), E2 = expf(A2-mx), E3 = expf(A3-mx);
        float den = E0 + E1 + E2 + E3;
        if (special) {
            wez[tid] = (E2 / den) * v.x;
        } else {
            int eslA = gA % 3, bA = gA / 3;
            int eslB = gB % 3, bB = gB / 3;
            float wA = ((eslA == 0) ? E0 : (eslA == 1) ? E1 : E3) / den;
            float wB = ((eslB == 0) ? E0 : (eslB == 1) ? E1 : E3) / den;
            atomicAdd(out + bA * NQ + tid, wA * v.x);
            atomicAdd(out + bB * NQ + tid, wB * v.y);
        }
    }
    if (special) {
        __syncthreads();
        for (int bb2 = tid; bb2 < 1024; bb2 += THREADS) {
            #pragma unroll
            for (int q = 0; q < NQ; ++q)
                atomicAdd(out + bb2 * NQ + q, wez[q]);
        }
    }
}

extern "C" void kernel_launch(void* const* d_in, const int* in_sizes, int n_in,
                              void* d_out, int out_size, void* d_ws, size_t ws_size,
                              hipStream_t stream) {
    const float* features = (const float*)d_in[0];
    const float* theta    = (const float*)d_in[1];
    const float* alpha    = (const float*)d_in[2];
    float* out = (float*)d_out;

    hipMemsetAsync(out, 0, (size_t)out_size * sizeof(float), stream);
    vqc_kernel<<<dim3(1537), THREADS, 0, stream>>>(features, theta, alpha, out);
}

// Round 14
// 122.360 us; speedup vs baseline: 1.0404x; 1.0102x over previous
//
#include <hip/hip_runtime.h>
#include <hip/hip_fp16.h>
#include <math.h>

#define NQ 12
#define DIM 4096
#define NL 4
#define THREADS 256
#define SWZC(e) ((e) ^ (((e) >> 3) & 14) ^ (((e) >> 7) & 15))
#define WAVEFENCE() { __builtin_amdgcn_wave_barrier(); __builtin_amdgcn_sched_barrier(0); }

typedef float v2f __attribute__((ext_vector_type(2)));

// native packed-f32 ops: clang lowers v2f32 fma/mul/add to v_pk_* on gfx90a+,
// with free neg modifiers -- no inline-asm register-constraint moves
__device__ __forceinline__ v2f pkfma(v2f a, v2f b, v2f c)  { return __builtin_elementwise_fma(a, b, c); }
__device__ __forceinline__ v2f pkfman(v2f a, v2f b, v2f c) { return __builtin_elementwise_fma(-a, b, c); }   // (-a)*b + c
__device__ __forceinline__ v2f pkmul(v2f a, v2f b)         { return a * b; }
__device__ __forceinline__ v2f pkmuln(v2f a, v2f b)        { return (-a) * b; }                              // (-a)*b
__device__ __forceinline__ v2f pkadd(v2f a, v2f b)         { return a + b; }
__device__ __forceinline__ float2 cmulS(float2 a, float2 b) {
    return make_float2(fmaf(a.x, b.x, -a.y * b.y), fmaf(a.x, b.y, a.y * b.x));
}

// f16 transit packing: (reA,reB) and (imA,imB) as two half2 in one uint2 (8B)
__device__ __forceinline__ uint2 packh(v2f re, v2f im) {
    __half2 a = __floats2half2_rn(re[0], re[1]);
    __half2 b = __floats2half2_rn(im[0], im[1]);
    uint2 r;
    r.x = __builtin_bit_cast(unsigned int, a);
    r.y = __builtin_bit_cast(unsigned int, b);
    return r;
}
__device__ __forceinline__ void unpackh(uint2 t, v2f* re, v2f* im) {
    float2 fa = __half22float2(__builtin_bit_cast(__half2, t.x));
    float2 fb = __half22float2(__builtin_bit_cast(__half2, t.y));
    v2f r = {fa.x, fa.y}, i = {fb.x, fb.y};
    *re = r; *im = i;
}

struct C2 { v2f r, i; };   // broadcast (re,re),(im,im); negation folded by compiler

// y  = K*x        : E = r*xre - i*xim ; I = i*xre + r*xim
#define CMUL_STD(orE, orI, K, xre, xim) \
    { orE = pkfman(K.i, xim, pkmul(K.r, xre)); orI = pkfma(K.i, xre, pkmul(K.r, xim)); }
// y += K*x
#define CMAC_STD(orE, orI, K, xre, xim) \
    { orE = pkfma(K.r, xre, pkfman(K.i, xim, orE)); orI = pkfma(K.r, xim, pkfma(K.i, xre, orI)); }
// y  = -conj(K)*x : E = -r*xre - i*xim ; I = i*xre - r*xim
#define CMUL_NCJ(orE, orI, K, xre, xim) \
    { orE = pkfman(K.i, xim, pkmuln(K.r, xre)); orI = pkfma(K.i, xre, pkmuln(K.r, xim)); }
// y += conj(K)*x  : E += r*xre + i*xim ; I += r*xim - i*xre
#define CMAC_CJ(orE, orI, K, xre, xim) \
    { orE = pkfma(K.r, xre, pkfma(K.i, xim, orE)); orI = pkfma(K.r, xim, pkfman(K.i, xre, orI)); }

// SU(2) 2-stage 4x4 pair-gate; even-CNOT baked in (outputs C<-y3, D<-y2).
#define QUADBODY(A_, B_, C_, D_) { \
    v2f z0r,z0i,z1r,z1i,z2r,z2i,z3r,z3i; \
    CMUL_STD(z0r,z0i, la, sre[A_], sim[A_]); CMAC_STD(z0r,z0i, lb, sre[B_], sim[B_]); \
    CMUL_NCJ(z1r,z1i, lb, sre[A_], sim[A_]); CMAC_CJ (z1r,z1i, la, sre[B_], sim[B_]); \
    CMUL_STD(z2r,z2i, la, sre[C_], sim[C_]); CMAC_STD(z2r,z2i, lb, sre[D_], sim[D_]); \
    CMUL_NCJ(z3r,z3i, lb, sre[C_], sim[C_]); CMAC_CJ (z3r,z3i, la, sre[D_], sim[D_]); \
    v2f y0r,y0i,y1r,y1i,y2r,y2i,y3r,y3i; \
    CMUL_STD(y0r,y0i, ha, z0r,z0i); CMAC_STD(y0r,y0i, hb, z2r,z2i); \
    CMUL_STD(y1r,y1i, ha, z1r,z1i); CMAC_STD(y1r,y1i, hb, z3r,z3i); \
    CMUL_NCJ(y2r,y2i, hb, z0r,z0i); CMAC_CJ (y2r,y2i, ha, z2r,z2i); \
    CMUL_NCJ(y3r,y3i, hb, z1r,z1i); CMAC_CJ (y3r,y3i, ha, z3r,z3i); \
    sre[A_]=y0r; sim[A_]=y0i; sre[B_]=y1r; sim[B_]=y1i; \
    sre[C_]=y3r; sim[C_]=y3i; sre[D_]=y2r; sim[D_]=y2i; }

#define LOADU \
    C2 la={U[0][0],U[0][1]}, lb={U[1][0],U[1][1]}, \
       ha={U[2][0],U[2][1]}, hb={U[3][0],U[3][1]};

__device__ __forceinline__ void pass_hi(v2f* sre, v2f* sim, const v2f (*U)[2]) {
    LOADU
    QUADBODY(0,4,8,12) QUADBODY(1,5,9,13) QUADBODY(2,6,10,14) QUADBODY(3,7,11,15)
}
__device__ __forceinline__ void pass_lo(v2f* sre, v2f* sim, const v2f (*U)[2]) {
    LOADU
    QUADBODY(0,1,2,3) QUADBODY(4,5,6,7) QUADBODY(8,9,10,11) QUADBODY(12,13,14,15)
}

__global__ __launch_bounds__(THREADS, 2)
void vqc_kernel(const float* __restrict__ features,
                const float* __restrict__ theta,
                const float* __restrict__ alpha,
                float* __restrict__ out)
{
    __shared__ uint2 scrH[DIM];           // 32 KB f16-packed transit (reA,reB,imA,imB)
    __shared__ v2f Upk[24][4][2];         // 1.5 KB coeff (r,i) pairs
    __shared__ v2f red[12 * 4];
    __shared__ float wez[12];

    // build-phase tables aliased into scrH (dead before first transition store)
    float2* cs = (float2*)scrH;                                     // [0,1152)
    float2 (*U48)[4] = (float2(*)[4])((char*)scrH + 1152);          // [1152,2688)
    float2 (*enc)[2] = (float2(*)[2])((char*)scrH + 2688);          // [2688,3072)
    float2 (*pairT)[4] = (float2(*)[4])((char*)scrH + 3072);        // [3072,3456)
    float2* loc = (float2*)((char*)scrH + 3456);                    // [3456,3712)

    const int tid = threadIdx.x;
    const bool special = (blockIdx.x == 0);   // shared h_angle_rx circuit (|+>^12 up to phase)
    const int gA = special ? 0 : 2 * ((int)blockIdx.x - 1);
    const int gB = gA + 1;

    // ---- stage 1: theta sincos + encoding states (2 circuits) ----
    if (tid < NL * NQ * 3) {
        float s, c; sincosf(0.5f * theta[tid], &s, &c);
        cs[tid] = make_float2(c, s);
    }
    if (tid >= 160 && tid < 184) {
        int c_ = (tid - 160) / 12, q = (tid - 160) % 12;
        const float r_ = 0.70710678118654752f;
        float2 a0, a1;
        if (special) { a0 = make_float2(r_, 0.f); a1 = a0; }
        else {
            int g = c_ ? gB : gA;
            int esl = g % 3, b = g / 3;
            float f = features[b * NQ + q];
            float s, c; sincosf(0.5f * f, &s, &c);
            if (esl == 0)      { a0 = make_float2(c, 0.f); a1 = make_float2(0.f, -s); }
            else if (esl == 1) { a0 = make_float2(c, 0.f); a1 = make_float2(s, 0.f); }
            else               { a0 = make_float2((c-s)*r_, 0.f); a1 = make_float2((c+s)*r_, 0.f); }
        }
        enc[c_ * NQ + q][0] = a0; enc[c_ * NQ + q][1] = a1;
    }
    __syncthreads();

    // ---- stage 2: fused U = RZ*RY*RX + pair tables ----
    if (tid < NL * NQ) {
        float c0 = cs[tid*3+0].x, s0 = cs[tid*3+0].y;
        float c1 = cs[tid*3+1].x, s1 = cs[tid*3+1].y;
        float c2 = cs[tid*3+2].x, s2 = cs[tid*3+2].y;
        float2 a00 = make_float2( c1*c0,  s1*s0);
        float2 a01 = make_float2(-s1*c0, -c1*s0);
        float2 a10 = make_float2( s1*c0, -c1*s0);
        float2 a11 = make_float2( c1*c0, -s1*s0);
        float2 ep = make_float2(c2, -s2), em = make_float2(c2, s2);
        U48[tid][0] = cmulS(ep, a00); U48[tid][1] = cmulS(ep, a01);
        U48[tid][2] = cmulS(em, a10); U48[tid][3] = cmulS(em, a11);
    }
    if (tid >= 64 && tid < 112) {
        int x = tid - 64;
        int c_ = x / 24, y = x % 24, p = y >> 2, v = y & 3;
        pairT[c_ * 6 + p][v] = cmulS(enc[c_*NQ + 2*p][v >> 1], enc[c_*NQ + 2*p + 1][v & 1]);
    }
    __syncthreads();

    // ---- stage 3: packed SU(2) coeff (r,i) pairs + local product table ----
    if (tid < 192) {
        int p = tid >> 3, rest = tid & 7, c = rest >> 1, comp = rest & 1;
        int l = p / 6, m = p % 6;
        int q = (c < 2) ? (2*m + 1) : (2*m);       // c0,c1: lo qubit a,b; c2,c3: hi qubit a,b
        float2 u = U48[l*NQ + q][c & 1];
        float xv = comp ? u.y : u.x;
        v2f vv = {xv, xv};
        Upk[p][c][comp] = vv;
    }
    if (tid >= 192 && tid < 224) {
        int x = tid - 192; int c_ = x >> 4, j = x & 15;
        loc[c_ * 16 + j] = cmulS(pairT[c_*6 + 4][j >> 2], pairT[c_*6 + 5][j & 3]);
    }
    __syncthreads();

    // ---- build product state into LA registers (i = tid<<4 | j) ----
    v2f sre[16], sim[16];
    {
        int t = tid;
        float2 preA = cmulS(cmulS(pairT[0][(t>>6)&3], pairT[1][(t>>4)&3]),
                            cmulS(pairT[2][(t>>2)&3], pairT[3][t&3]));
        float2 preB = cmulS(cmulS(pairT[6][(t>>6)&3], pairT[7][(t>>4)&3]),
                            cmulS(pairT[8][(t>>2)&3], pairT[9][t&3]));
        #pragma unroll
        for (int j = 0; j < 16; ++j) {
            float2 aA = cmulS(preA, loc[j]);
            float2 aB = cmulS(preB, loc[16 + j]);
            v2f r = {aA.x, aB.x}, ii = {aA.y, aB.y};
            sre[j] = r; sim[j] = ii;
        }
    }
    __syncthreads();   // tables (aliased in scrH) dead before first transition store

    const int ba = SWZC(tid << 4);
    const int bb = SWZC((((tid >> 4) << 8) | (tid & 15)));
    const int bc = SWZC(tid);
    const int sx = (tid << 4) ^ ((tid & 1) << 3) ^ (((tid >> 2) & 1) << 5)
                             ^ (((tid >> 4) & 1) << 7) ^ (((tid >> 6) & 1) << 9);
    const int bs = SWZC(sx);

    // ---- 4 variational layers: f16 transit, minimal barrier schedule ----
    #pragma unroll 1
    for (int l = 0; l < NL; ++l) {
        if (l > 0) {
            // LA entry: sigma-folded gather (cross-thread reads of T_CA stores)
            #pragma unroll
            for (int qq = 0; qq < 4; ++qq)
            #pragma unroll
            for (int rr = 0; rr < 4; ++rr) {
                int j = 4 * rr + qq;
                int a = bs ^ (j ^ ((j >> 1) & 2));
                unpackh(scrH[a], &sre[j], &sim[j]);
            }
            __syncthreads();   // all gathers done before T_AB overwrites (cross WAR)
        }
        // LA: P4 (bits 3,2), P5 (bits 1,0)
        pass_hi(sre, sim, Upk[l*6 + 4]);
        pass_lo(sre, sim, Upk[l*6 + 5]);
        // T_AB: write own 16-block (ba), read wave-local cross (bb)
        WAVEFENCE();
        #pragma unroll
        for (int j = 0; j < 16; ++j) scrH[ba ^ j] = packh(sre[j], sim[j]);
        WAVEFENCE();
        #pragma unroll
        for (int qq = 0; qq < 4; ++qq)
        #pragma unroll
        for (int rr = 0; rr < 4; ++rr) {
            int j = 4 * rr + qq;
            unpackh(scrH[bb ^ SWZC(j << 4)], &sre[j], &sim[j]);
        }
        // LB: P2 (bits 7,6), P3 (bits 5,4)
        pass_hi(sre, sim, Upk[l*6 + 2]);
        pass_lo(sre, sim, Upk[l*6 + 3]);
        // T_BC: write own set (bb), cross gather (bc)
        WAVEFENCE();
        #pragma unroll
        for (int j = 0; j < 16; ++j) scrH[bb ^ SWZC(j << 4)] = packh(sre[j], sim[j]);
        __syncthreads();
        #pragma unroll
        for (int qq = 0; qq < 4; ++qq)
        #pragma unroll
        for (int rr = 0; rr < 4; ++rr) {
            int j = 4 * rr + qq;
            unpackh(scrH[bc ^ SWZC(j << 8)], &sre[j], &sim[j]);
        }
        // LC: P0 (bits 11,10), P1 (bits 9,8)
        pass_hi(sre, sim, Upk[l*6 + 0]);
        pass_lo(sre, sim, Upk[l*6 + 1]);
        if (l < NL - 1) {
            // T_CA: write own set (bc); next LA gather is cross -> barrier after
            WAVEFENCE();
            #pragma unroll
            for (int j = 0; j < 16; ++j) scrH[bc ^ SWZC(j << 8)] = packh(sre[j], sim[j]);
            __syncthreads();
        }
    }

    // ---- measurement in LC, layer-3 sigma folded into sign indices ----
    v2f s0 = {0.f,0.f}, s1 = {0.f,0.f}, s2 = {0.f,0.f}, s3 = {0.f,0.f}, psum = {0.f,0.f};
    {
        #pragma unroll
        for (int j = 0; j < 16; ++j) {
            v2f p = pkfma(sim[j], sim[j], pkmul(sre[j], sre[j]));
            psum = pkadd(psum, p);
            if (j & 8)                        s0 = s0 - p; else s0 = s0 + p;
            if (j & 4)                        s1 = s1 - p; else s1 = s1 + p;
            if ((((j >> 1) ^ (j >> 2)) & 1))  s2 = s2 - p; else s2 = s2 + p;
            if (j & 1)                        s3 = s3 - p; else s3 = s3 + p;
        }
    }
    v2f vals[12];
    {
        int t = tid;
        int mt = t ^ ((t >> 1) & 0xAA);
        vals[0] = s0; vals[1] = s1; vals[2] = s2; vals[3] = s3;
        vals[4]  = ((t >> 7) & 1)  ? -s3 : s3;
        vals[5]  = ((mt >> 6) & 1) ? -psum : psum;
        vals[6]  = ((mt >> 5) & 1) ? -psum : psum;
        vals[7]  = ((mt >> 4) & 1) ? -psum : psum;
        vals[8]  = ((mt >> 3) & 1) ? -psum : psum;
        vals[9]  = ((mt >> 2) & 1) ? -psum : psum;
        vals[10] = ((mt >> 1) & 1) ? -psum : psum;
        vals[11] = (mt & 1)        ? -psum : psum;
    }
    const int lane = tid & 63, wv = tid >> 6;
    #pragma unroll
    for (int q = 0; q < 12; ++q) {
        v2f v = vals[q];
        #pragma unroll
        for (int mm = 32; mm >= 1; mm >>= 1) {
            v.x += __shfl_xor(v.x, mm, 64);
            v.y += __shfl_xor(v.y, mm, 64);
        }
        if (lane == 0) red[q * 4 + wv] = v;
    }
    __syncthreads();

    if (tid < 12) {
        v2f v = pkadd(pkadd(red[tid*4+0], red[tid*4+1]), pkadd(red[tid*4+2], red[tid*4+3]));
        float A0 = alpha[0], A1 = alpha[1], A2 = alpha[2], A3 = alpha[3];
        float mx = fmaxf(fmaxf(A0, A1), fmaxf(A2, A3));
        float E0 = expf(A0-mx), E1 = expf(A1-mx), E2 = expf(A2-mx), E3 = expf(A3-mx);
        float den = E0 + E1 + E2 + E3;
        if (special) {
            wez[tid] = (E2 / den) * v.x;
        } else {
            int eslA = gA % 3, bA = gA / 3;
            int eslB = gB % 3, bB = gB / 3;
            float wA = ((eslA == 0) ? E0 : (eslA == 1) ? E1 : E3) / den;
            float wB = ((eslB == 0) ? E0 : (eslB == 1) ? E1 : E3) / den;
            atomicAdd(out + bA * NQ + tid, wA * v.x);
            atomicAdd(out + bB * NQ + tid, wB * v.y);
        }
    }
    if (special) {
        __syncthreads();
        for (int bb2 = tid; bb2 < 1024; bb2 += THREADS) {
            #pragma unroll
            for (int q = 0; q < NQ; ++q)
                atomicAdd(out + bb2 * NQ + q, wez[q]);
        }
    }
}

extern "C" void kernel_launch(void* const* d_in, const int* in_sizes, int n_in,
                              void* d_out, int out_size, void* d_ws, size_t ws_size,
                              hipStream_t stream) {
    const float* features = (const float*)d_in[0];
    const float* theta    = (const float*)d_in[1];
    const float* alpha    = (const float*)d_in[2];
    float* out = (float*)d_out;

    hipMemsetAsync(out, 0, (size_t)out_size * sizeof(float), stream);
    vqc_kernel<<<dim3(1537), THREADS, 0, stream>>>(features, theta, alpha, out);
}